// Round 1
// baseline (179.044 us; speedup 1.0000x reference)
//
#include <hip/hip_runtime.h>
#include <math.h>

// Monotone cubic spline flow (neural spline flow, cubic variant).
// B*D = 2,097,152 elements, K = 8 bins.
// R3: latency-bound fix (VALUBusy 33%, HBM 20%, both pipes idle):
//  - 4 elements per thread, fully unrolled -> 4 independent dependency
//    chains per wave for the scheduler to interleave (VGPR 28 -> ~100,
//    headroom was enormous). x/dl/dr/out/lad become float4 accesses.
//  - softmax without max-subtraction (inputs ~N(0,1), exp cannot overflow;
//    absmax tolerance is 0.0156).
//  - slopes are strictly positive (h,w >= MIN_BIN) => sign terms == 2,
//    abs free; fold 0.5*(...)*2 into min(2*min(s,s'), num*rcp(den)).
//  - bin search + gather fused into one monotone-predicate select chain
//    (cw increasing => t>=cw[k] predicates are monotone in k).

constexpr int K = 8;
constexpr int E = 4;               // elements per thread
constexpr float TAIL = 3.0f;
constexpr float MIN_BIN = 0.001f;

__device__ __forceinline__ float rcpf(float v) {
    return __builtin_amdgcn_rcpf(v);   // v_rcp_f32, ~1 ulp
}

__global__ __launch_bounds__(256, 4) void cbs_kernel(
    const float* __restrict__ x_,
    const float* __restrict__ w_,
    const float* __restrict__ h_,
    const float* __restrict__ dl_,
    const float* __restrict__ dr_,
    float* __restrict__ out,
    float* __restrict__ lad,
    int n)
{
    int tid  = blockIdx.x * blockDim.x + threadIdx.x;
    int base = tid * E;
    if (base >= n) return;

    // ---- issue all global loads up front (max MLP per wave) ----
    float4 xv4 = *(const float4*)(x_  + base);
    float4 dl4 = *(const float4*)(dl_ + base);
    float4 dr4 = *(const float4*)(dr_ + base);
    const float4* w4 = (const float4*)w_ + 2 * (size_t)base;
    const float4* h4 = (const float4*)h_ + 2 * (size_t)base;

    float wv[E][K], hv[E][K];
    #pragma unroll
    for (int e = 0; e < E; e++) {
        float4 a = w4[2 * e], b = w4[2 * e + 1];
        wv[e][0] = a.x; wv[e][1] = a.y; wv[e][2] = a.z; wv[e][3] = a.w;
        wv[e][4] = b.x; wv[e][5] = b.y; wv[e][6] = b.z; wv[e][7] = b.w;
    }
    #pragma unroll
    for (int e = 0; e < E; e++) {
        float4 a = h4[2 * e], b = h4[2 * e + 1];
        hv[e][0] = a.x; hv[e][1] = a.y; hv[e][2] = a.z; hv[e][3] = a.w;
        hv[e][4] = b.x; hv[e][5] = b.y; hv[e][6] = b.z; hv[e][7] = b.w;
    }

    float xs[E]  = {xv4.x, xv4.y, xv4.z, xv4.w};
    float dls[E] = {dl4.x, dl4.y, dl4.z, dl4.w};
    float drs[E] = {dr4.x, dr4.y, dr4.z, dr4.w};
    float outs[E], lads[E];

    #pragma unroll
    for (int e = 0; e < E; e++) {
        // ---- softmax + min-bin affine (no max-subtraction needed) ----
        float wr[K], hr[K];
        float sw = 0.0f, sh = 0.0f;
        #pragma unroll
        for (int k = 0; k < K; k++) { wr[k] = __expf(wv[e][k]); sw += wr[k]; }
        #pragma unroll
        for (int k = 0; k < K; k++) { hr[k] = __expf(hv[e][k]); sh += hr[k]; }
        float cwf = (1.0f - MIN_BIN * K) * rcpf(sw);
        float chf = (1.0f - MIN_BIN * K) * rcpf(sh);
        #pragma unroll
        for (int k = 0; k < K; k++) {
            wr[k] = fmaf(wr[k], cwf, MIN_BIN);
            hr[k] = fmaf(hr[k], chf, MIN_BIN);
        }

        // ---- cumulative knots + slopes (all strictly positive) ----
        float cw[K + 1], ch[K + 1], s[K];
        cw[0] = 0.0f; ch[0] = 0.0f;
        #pragma unroll
        for (int k = 0; k < K; k++) {
            cw[k + 1] = cw[k] + wr[k];
            ch[k + 1] = ch[k] + hr[k];
            s[k] = hr[k] * rcpf(wr[k]);
        }

        // ---- derivatives: endpoints (sigmoid) + interior (monotone) ----
        float dv[K + 1];
        dv[0] = 3.0f * s[0]     * rcpf(1.0f + __expf(-dls[e]));
        dv[K] = 3.0f * s[K - 1] * rcpf(1.0f + __expf(-drs[e]));
        #pragma unroll
        for (int k = 0; k < K - 1; k++) {
            float num = wr[k + 1] * s[k] + wr[k] * s[k + 1];
            dv[k + 1] = fminf(2.0f * fminf(s[k], s[k + 1]),
                              num * rcpf(wr[k] + wr[k + 1]));
        }

        // ---- normalized position ----
        float xv = xs[e];
        float t = fminf(fmaxf((xv + TAIL) * (1.0f / (2.0f * TAIL)), 0.0f), 1.0f);

        // ---- fused bin-search + gather via monotone predicates ----
        // cw is strictly increasing, so (t >= cw[k]) is monotone in k:
        // the last k where it holds is the bin.  One cmp + 6 cndmask per k.
        float wk = wr[0], sk = s[0], d0 = dv[0], d1 = dv[1], lw = 0.0f, dd = 0.0f;
        #pragma unroll
        for (int k = 1; k < K; k++) {
            bool p = (t >= cw[k]);
            wk = p ? wr[k]     : wk;
            sk = p ? s[k]      : sk;
            d0 = p ? dv[k]     : d0;
            d1 = p ? dv[k + 1] : d1;
            lw = p ? cw[k]     : lw;
            dd = p ? ch[k]     : dd;
        }

        // ---- cubic evaluation ----
        float iw = rcpf(wk);
        float ia = (d0 + d1 - 2.0f * sk) * iw * iw;
        float ib = (3.0f * sk - 2.0f * d0 - d1) * iw;
        float sx = t - lw;
        float out_s = ((ia * sx + ib) * sx + d0) * sx + dd;
        float der   = (3.0f * ia * sx + 2.0f * ib) * sx + d0;
        float lad_s = __logf(fabsf(der));   // + log(6) - log(6) == 0

        out_s = fminf(fmaxf(out_s, 0.0f), 1.0f) * (2.0f * TAIL) - TAIL;

        bool inside = (xv >= -TAIL) && (xv <= TAIL);
        outs[e] = inside ? out_s : xv;
        lads[e] = inside ? lad_s : 0.0f;
    }

    *(float4*)(out + base) = make_float4(outs[0], outs[1], outs[2], outs[3]);
    *(float4*)(lad + base) = make_float4(lads[0], lads[1], lads[2], lads[3]);
}

extern "C" void kernel_launch(void* const* d_in, const int* in_sizes, int n_in,
                              void* d_out, int out_size, void* d_ws, size_t ws_size,
                              hipStream_t stream) {
    const float* x  = (const float*)d_in[0];
    const float* w  = (const float*)d_in[1];
    const float* h  = (const float*)d_in[2];
    const float* dl = (const float*)d_in[3];
    const float* dr = (const float*)d_in[4];
    int n = in_sizes[0];               // 8192*256 = 2,097,152
    float* out = (float*)d_out;        // outputs, then logabsdet, concatenated
    float* lad = out + n;

    const int threads = 256;
    const int elems_per_block = threads * E;
    const int blocks = (n + elems_per_block - 1) / elems_per_block;   // 2048
    cbs_kernel<<<blocks, threads, 0, stream>>>(x, w, h, dl, dr, out, lad, n);
}

// Round 2
// 175.633 us; speedup vs baseline: 1.0194x; 1.0194x over previous
//
#include <hip/hip_runtime.h>
#include <math.h>

// Monotone cubic spline flow. B*D = 2,097,152 elements, K = 8 bins.
// R4: request-rate theory. R2/R3 both stuck at ~62-65us with VALUBusy 21-33%,
// HBM 20% -> external limit. The w_/h_ loads (84% of read bytes) are float4
// at 32B lane-stride: every wave-instruction touches half of each cache line,
// doubling TA/TCP line requests per byte vs a dense stream (~39 G req/s
// sustained ~= the dense-copy request ceiling). Fix: dense 16B/lane global
// loads -> wave-private XOR-swizzled LDS tiles -> per-element ds_read_b128.
// Swizzle off^((off>>3)&0x70): writes (16B stride) and reads (32B stride)
// both cover all 8 bank-groups uniformly -> conflict-free. No barriers
// (tiles are wave-private). E=1 (R3's E=4 regressed); keeps R3's verified
// algebra: no-max softmax, positive slopes => sign terms == 2, fused
// monotone-predicate bin search.

constexpr int K = 8;
constexpr float TAIL = 3.0f;
constexpr float MIN_BIN = 0.001f;

__device__ __forceinline__ float rcpf(float v) {
    return __builtin_amdgcn_rcpf(v);   // v_rcp_f32, ~1 ulp
}

__device__ __forceinline__ unsigned swz(unsigned off) {
    // involution on [0,2048), 16B-aligned preserved: bank-group bits [6:4]
    // get XORed with address bits [9:7]
    return off ^ ((off >> 3) & 0x70u);
}

__global__ __launch_bounds__(256) void cbs_kernel(
    const float* __restrict__ x_,
    const float* __restrict__ w_,
    const float* __restrict__ h_,
    const float* __restrict__ dl_,
    const float* __restrict__ dr_,
    float* __restrict__ out,
    float* __restrict__ lad,
    int n)
{
    __shared__ __align__(16) unsigned char lds[16384];   // 4 waves x (2KB w + 2KB h)

    int i = blockIdx.x * blockDim.x + threadIdx.x;
    if (i >= n) return;

    int wave = threadIdx.x >> 6;
    int lane = threadIdx.x & 63;
    size_t ebase = (size_t)blockIdx.x * 256 + (size_t)wave * 64;  // wave's first element

    const char* wg = (const char*)w_ + ebase * 32;   // 32 B per element
    const char* hg = (const char*)h_ + ebase * 32;
    unsigned wb = (unsigned)wave * 4096u;            // w tile base in LDS
    unsigned hb = wb + 2048u;

    // ---- stage: dense global (16B/lane contiguous) -> swizzled LDS ----
    #pragma unroll
    for (int r = 0; r < 2; r++) {
        unsigned off = (unsigned)(r * 1024 + 16 * lane);
        float4 vw = *(const float4*)(wg + off);
        float4 vh = *(const float4*)(hg + off);
        *(float4*)(&lds[wb + swz(off)]) = vw;
        *(float4*)(&lds[hb + swz(off)]) = vh;
    }

    // small dense loads (x, dl, dr) overlap the staging latency
    float xv  = x_[i];
    float dlv = dl_[i];
    float drv = dr_[i];

    // ---- read own element back (wave-private: compiler's lgkmcnt suffices) ----
    unsigned o0 = 32u * (unsigned)lane;
    float4 wa  = *(const float4*)(&lds[wb + swz(o0)]);
    float4 wbv = *(const float4*)(&lds[wb + swz(o0 + 16u)]);
    float4 ha  = *(const float4*)(&lds[hb + swz(o0)]);
    float4 hbv = *(const float4*)(&lds[hb + swz(o0 + 16u)]);

    float wr[K] = {wa.x, wa.y, wa.z, wa.w, wbv.x, wbv.y, wbv.z, wbv.w};
    float hr[K] = {ha.x, ha.y, ha.z, ha.w, hbv.x, hbv.y, hbv.z, hbv.w};

    // ---- softmax + min-bin affine (no max-subtraction; inputs ~N(0,1)) ----
    float sw = 0.0f, sh = 0.0f;
    #pragma unroll
    for (int k = 0; k < K; k++) { wr[k] = __expf(wr[k]); sw += wr[k]; }
    #pragma unroll
    for (int k = 0; k < K; k++) { hr[k] = __expf(hr[k]); sh += hr[k]; }
    float cwf = (1.0f - MIN_BIN * K) * rcpf(sw);
    float chf = (1.0f - MIN_BIN * K) * rcpf(sh);
    #pragma unroll
    for (int k = 0; k < K; k++) {
        wr[k] = fmaf(wr[k], cwf, MIN_BIN);
        hr[k] = fmaf(hr[k], chf, MIN_BIN);
    }

    // ---- cumulative knots + slopes (all strictly positive) ----
    float cw[K + 1], ch[K + 1], s[K];
    cw[0] = 0.0f; ch[0] = 0.0f;
    #pragma unroll
    for (int k = 0; k < K; k++) {
        cw[k + 1] = cw[k] + wr[k];
        ch[k + 1] = ch[k] + hr[k];
        s[k] = hr[k] * rcpf(wr[k]);
    }

    // ---- derivatives: endpoints (sigmoid) + interior (monotone) ----
    float dv[K + 1];
    dv[0] = 3.0f * s[0]     * rcpf(1.0f + __expf(-dlv));
    dv[K] = 3.0f * s[K - 1] * rcpf(1.0f + __expf(-drv));
    #pragma unroll
    for (int k = 0; k < K - 1; k++) {
        float num = wr[k + 1] * s[k] + wr[k] * s[k + 1];
        dv[k + 1] = fminf(2.0f * fminf(s[k], s[k + 1]),
                          num * rcpf(wr[k] + wr[k + 1]));
    }

    // ---- normalized position ----
    float t = fminf(fmaxf((xv + TAIL) * (1.0f / (2.0f * TAIL)), 0.0f), 1.0f);

    // ---- fused bin-search + gather via monotone predicates ----
    float wk = wr[0], sk = s[0], d0 = dv[0], d1 = dv[1], lw = 0.0f, dd = 0.0f;
    #pragma unroll
    for (int k = 1; k < K; k++) {
        bool p = (t >= cw[k]);
        wk = p ? wr[k]     : wk;
        sk = p ? s[k]      : sk;
        d0 = p ? dv[k]     : d0;
        d1 = p ? dv[k + 1] : d1;
        lw = p ? cw[k]     : lw;
        dd = p ? ch[k]     : dd;
    }

    // ---- cubic evaluation ----
    float iw = rcpf(wk);
    float ia = (d0 + d1 - 2.0f * sk) * iw * iw;
    float ib = (3.0f * sk - 2.0f * d0 - d1) * iw;
    float sx = t - lw;
    float out_s = ((ia * sx + ib) * sx + d0) * sx + dd;
    float der   = (3.0f * ia * sx + 2.0f * ib) * sx + d0;
    float lad_s = __logf(fabsf(der));   // + log(6) - log(6) == 0

    out_s = fminf(fmaxf(out_s, 0.0f), 1.0f) * (2.0f * TAIL) - TAIL;

    bool inside = (xv >= -TAIL) && (xv <= TAIL);
    out[i] = inside ? out_s : xv;
    lad[i] = inside ? lad_s : 0.0f;
}

extern "C" void kernel_launch(void* const* d_in, const int* in_sizes, int n_in,
                              void* d_out, int out_size, void* d_ws, size_t ws_size,
                              hipStream_t stream) {
    const float* x  = (const float*)d_in[0];
    const float* w  = (const float*)d_in[1];
    const float* h  = (const float*)d_in[2];
    const float* dl = (const float*)d_in[3];
    const float* dr = (const float*)d_in[4];
    int n = in_sizes[0];               // 8192*256 = 2,097,152
    float* out = (float*)d_out;        // outputs, then logabsdet, concatenated
    float* lad = out + n;

    const int threads = 256;
    const int blocks = (n + threads - 1) / threads;   // 8192
    cbs_kernel<<<blocks, threads, 0, stream>>>(x, w, h, dl, dr, out, lad, n);
}